// Round 9
// baseline (62.616 us; speedup 1.0000x reference)
//
#include <hip/hip_runtime.h>
#include <math.h>

#define NCLS 81
#define A_ANCH 8732
#define B_BATCH 64
#define NANCH (B_BATCH * A_ANCH)   // 558,848 anchors
#define EPSF 1e-7f

// ---- K1: 8 anchors/tile, per-wave double-buffered pipeline, 8 waves/block ----
#define TILE 8
#define TDW  (TILE * NCLS)      // 648 dwords/tile
#define BUFDW 768               // 3*256 staged dwords (120-dw over-read into pad)
#define WPB 8                   // waves per block (independent pipelines, no barriers)
#define BLK (WPB * 64)          // 512 threads
#define GRIDB 768               // 3 blocks/CU * 256 CU
#define NWAVES (GRIDB * WPB)    // 6144 wave pipelines
#define NT (NANCH / TILE)       // 69,856 tiles (exact)

// ---------------- workspace layout ----------------
// [0]      sout : NANCH floats (-logp0 per anchor)
// [SBYTES] accum: 2 doubles (conf_sum, loc_sum)
// [+16]    hits : 1 ull
static const size_t SBYTES = (size_t)NANCH * sizeof(float);

#define GLOAD_LDS16(g, l) __builtin_amdgcn_global_load_lds( \
    (const __attribute__((address_space(1))) void*)(g),      \
    (__attribute__((address_space(3))) void*)(l), 16, 0, 0)

// exactly 3 vmem ops; LDS dst is wave-uniform base (HW scatters lane*16B)
__device__ __forceinline__ void stage_tile(const float* __restrict__ g,
                                           float* lb, int ln) {
    #pragma unroll
    for (int c = 0; c < 3; ++c) {
        GLOAD_LDS16(g + c * 256 + ln * 4, lb + c * 256);
    }
}

// ---------------- K1: streaming -logp0 (lse - x0) per anchor ----------------
// 8 INDEPENDENT single-wave pipelines per 512-thread block, each with its own
// 2x768-dword LDS slice (48 KB/block -> 3 blocks/CU -> 24 waves/CU = 6/SIMD).
// No __syncthreads anywhere; vmcnt is per-wave so each pipeline's counted-wait
// protocol is private. Loop vmem/iter = 3 stage + 1 masked store -> vmcnt(3)
// drains tile t (and the 1-iter-old store) while tile t+1 stays in flight.
__global__ __launch_bounds__(BLK, 6) void lse_kernel(
    const float* __restrict__ conf, float* __restrict__ sout,
    double* __restrict__ accum, unsigned long long* __restrict__ hits)
{
    __shared__ float sb[WPB][2][BUFDW];   // 49,152 B

    int tid = threadIdx.x;
    int wv = tid >> 6, ln = tid & 63;
    if (blockIdx.x == 0 && tid == 0) {    // consumers run in later kernels
        accum[0] = 0.0; accum[1] = 0.0; *hits = 0ull;
    }

    int w = blockIdx.x * WPB + wv;        // global wave id: tiles w, w+NWAVES, ...
    int a = ln >> 3, l = ln & 7;          // 8 lanes/anchor; lane l: classes l*10..l*10+9 (+80 on l==7)

    int t = w;                            // w < NWAVES <= NT always
    stage_tile(conf + (size_t)t * TDW, &sb[wv][0][0], ln);
    int par = 0;

    #pragma clang loop unroll(disable)
    for (; t < NT; t += NWAVES) {
        int tn = t + NWAVES;
        bool more = (tn < NT);
        if (more) stage_tile(conf + (size_t)tn * TDW, &sb[wv][par ^ 1][0], ln);

        // queue (old->new): [stage(t) x3, store(t-1), stage(tn) x3]
        // vmcnt(3): all but newest 3 retired -> stage(t) landed, next stays in flight
        if (more) { asm volatile("s_waitcnt vmcnt(3)" ::: "memory"); }
        else      { asm volatile("s_waitcnt vmcnt(0)" ::: "memory"); }
        __builtin_amdgcn_sched_barrier(0);

        const float* r = &sb[wv][par][a * 81 + l * 10];
        float x0 = r[0];                  // meaningful on l==0
        float e0 = 0.f, e1 = 0.f;
        #pragma unroll
        for (int j = 0; j < 10; j += 2) {
            e0 += __expf(r[j]);
            e1 += __expf(r[j + 1]);
        }
        float s = e0 + e1;
        if (l == 7) s += __expf(r[10]);   // class 80
        s += __shfl_xor(s, 1);
        s += __shfl_xor(s, 2);
        s += __shfl_xor(s, 4);            // 8-lane group sum
        if (l == 0) sout[(size_t)t * TILE + a] = __logf(s) - x0;  // 8 lanes -> 32B store

        par ^= 1;
    }
}

// ---------------- K2: per-batch positives + hard-negative mining ----------------
#define K2_T 1024
#define VPT 9   // ceil(8732/1024)

__global__ __launch_bounds__(K2_T) void mine_kernel(
    const float* __restrict__ conf, const float* __restrict__ loc,
    const float* __restrict__ tgt, const float* __restrict__ sout,
    double* __restrict__ accum, unsigned long long* __restrict__ hits)
{
    __shared__ int   cnt[34];   // slots 0..30: bisect iters, 32: c0, 33: cg
    __shared__ float fs[4];     // 0: sall, 1: sg, 2: pos_ce, 3: pos_loc
    __shared__ int   nm_s;
    int b = blockIdx.x, tid = threadIdx.x, lane = tid & 63;
    if (tid < 34) cnt[tid] = 0;
    if (tid < 4)  fs[tid] = 0.f;
    if (tid == 0) nm_s = 0;
    __syncthreads();

    float v[VPT]; int lab[VPT];
    size_t base = (size_t)b * A_ANCH;
    #pragma unroll
    for (int i = 0; i < VPT; ++i) {
        int idx = tid + i * K2_T;
        bool in = idx < A_ANCH;
        v[i]   = in ? sout[base + idx] : -1.f;
        lab[i] = in ? (int)tgt[(base + idx) * 5 + 4] : 0;
    }

    // ---- positives: CE correction + GIoU; mask out of mining ----
    float pce = 0.f, ploc = 0.f; int pc = 0;
    #pragma unroll
    for (int i = 0; i < VPT; ++i) {
        if (lab[i] > 0) {
            size_t gi = base + (size_t)(tid + i * K2_T);
            float r0 = conf[gi * NCLS];
            float rl = conf[gi * NCLS + lab[i]];
            pce += v[i] + r0 - rl;       // ce = (lse - r0) + r0 - rl
            float4 p = *(const float4*)(loc + gi * 4);
            const float* tg = tgt + gi * 5;
            float tx1 = tg[0], ty1 = tg[1], tx2 = tg[2], ty2 = tg[3];
            float area_p = (p.z - p.x) * (p.w - p.y);
            float area_t = (tx2 - tx1) * (ty2 - ty1);
            float iw = fmaxf(fminf(p.z, tx2) - fmaxf(p.x, tx1), 0.f);
            float ih = fmaxf(fminf(p.w, ty2) - fmaxf(p.y, ty1), 0.f);
            float inter = iw * ih;
            float uni   = area_p + area_t - inter;
            float iou   = inter / (uni + EPSF);
            float cw = fmaxf(p.z, tx2) - fminf(p.x, tx1);
            float ch = fmaxf(p.w, ty2) - fminf(p.y, ty1);
            float area_c = cw * ch;
            ploc += 1.f - (iou - (area_c - uni) / (area_c + EPSF));
            pc++;
            v[i] = -1.f;                 // exclude from mining
        }
    }
    for (int off = 32; off; off >>= 1) {
        pc   += __shfl_xor(pc, off);
        pce  += __shfl_xor(pce, off);
        ploc += __shfl_xor(ploc, off);
    }
    if (lane == 0) {
        if (pc) atomicAdd(&nm_s, pc);
        atomicAdd(&fs[2], pce);
        atomicAdd(&fs[3], ploc);
    }

    // ---- count & sum of all mining candidates (v >= 0) ----
    int c = 0; float sa = 0.f;
    #pragma unroll
    for (int i = 0; i < VPT; ++i) { if (v[i] >= 0.f) { c++; sa += v[i]; } }
    for (int off = 32; off; off >>= 1) { c += __shfl_xor(c, off); sa += __shfl_xor(sa, off); }
    if (lane == 0) { atomicAdd(&cnt[32], c); atomicAdd(&fs[0], sa); }
    __syncthreads();

    int k = 3 * nm_s;
    int c0 = cnt[32]; float sall = fs[0];
    float negl = 0.f;
    if (k >= c0) {
        negl = sall;
    } else if (k > 0) {
        // bisect IEEE bits for the k-th largest candidate (values > 0)
        unsigned lo = 0u, hi = 0x7F800000u;
        int it = 0;
        while (hi - lo > 1u) {           // 31 uniform iterations
            unsigned mid = lo + (hi - lo) / 2u;
            float thr = __uint_as_float(mid);
            int cc = 0;
            #pragma unroll
            for (int i = 0; i < VPT; ++i) cc += (v[i] >= thr) ? 1 : 0;
            for (int off = 32; off; off >>= 1) cc += __shfl_xor(cc, off);
            if (lane == 0) atomicAdd(&cnt[it], cc);
            __syncthreads();
            if (cnt[it] >= k) lo = mid; else hi = mid;
            ++it;
        }
        float tth = __uint_as_float(lo); // exact k-th largest value
        int cg = 0; float sg = 0.f;
        #pragma unroll
        for (int i = 0; i < VPT; ++i) { if (v[i] > tth) { cg++; sg += v[i]; } }
        for (int off = 32; off; off >>= 1) { cg += __shfl_xor(cg, off); sg += __shfl_xor(sg, off); }
        if (lane == 0) { atomicAdd(&cnt[33], cg); atomicAdd(&fs[1], sg); }
        __syncthreads();
        negl = fs[1] + (float)(k - cnt[33]) * tth;   // ties contribute value tth
    }

    if (tid == 0) {
        atomicAdd(&accum[0], (double)(fs[2] + negl));
        atomicAdd(&accum[1], (double)fs[3]);
        atomicAdd(hits, (unsigned long long)nm_s);
    }
}

// ---------------- K3: finalize ----------------
__global__ void finalize_kernel(const double* __restrict__ accum,
                                const unsigned long long* __restrict__ hits,
                                float* __restrict__ out) {
    if (threadIdx.x == 0 && blockIdx.x == 0) {
        double conf_s = accum[0], loc_s = accum[1];
        unsigned long long h = *hits;
        double denom = (double)(h > 0 ? h : 1ull);
        if (h > 0) {
            out[0] = (float)((conf_s + loc_s) / denom);
            out[1] = (float)(conf_s / denom);
            out[2] = (float)(loc_s / denom);
        } else {
            out[0] = 0.f; out[1] = 0.f; out[2] = 0.f;
        }
    }
}

extern "C" void kernel_launch(void* const* d_in, const int* in_sizes, int n_in,
                              void* d_out, int out_size, void* d_ws, size_t ws_size,
                              hipStream_t stream) {
    const float* conf = (const float*)d_in[0];
    const float* loc  = (const float*)d_in[1];
    const float* tgt  = (const float*)d_in[2];
    float* out = (float*)d_out;

    char* ws = (char*)d_ws;
    float* sout = (float*)ws;
    double* accum = (double*)(ws + SBYTES);
    unsigned long long* hits = (unsigned long long*)(ws + SBYTES + 16);

    lse_kernel<<<dim3(GRIDB), dim3(BLK), 0, stream>>>(conf, sout, accum, hits);
    mine_kernel<<<dim3(B_BATCH), dim3(K2_T), 0, stream>>>(
        conf, loc, tgt, sout, accum, hits);
    finalize_kernel<<<1, 64, 0, stream>>>(accum, hits, out);
}